// Round 3
// baseline (437.132 us; speedup 1.0000x reference)
//
#include <hip/hip_runtime.h>
#include <stdint.h>

typedef unsigned short u16;
typedef __attribute__((ext_vector_type(8))) __bf16 bf16x8;
typedef __attribute__((ext_vector_type(4))) float f32x4;

#define MAXMT 40
#define N_TOK 2048
#define DDIM 1024
#define FDIM 1024

#define DEV static __device__ __forceinline__

DEV float bf2f(u16 u) {
    union { uint32_t i; float f; } v;
    v.i = ((uint32_t)u) << 16;
    return v.f;
}
DEV u16 f2bf(float f) {
    union { float f; uint32_t i; } v;
    v.f = f;
    uint32_t x = v.i;
    return (u16)((x + 0x7fffu + ((x >> 16) & 1u)) >> 16);  // RNE
}

// ---------------- dtype detection: bf16 stream vs fp32-reinterpreted ----------------
__global__ void k_detect(const u16* __restrict__ xr, int* __restrict__ dflag) {
    __shared__ int cnt;
    if (threadIdx.x == 0) cnt = 0;
    __syncthreads();
    u16 u = xr[threadIdx.x];            // 512 samples
    int e = (u >> 7) & 0xff;
    int insane = (e != 0) && (e < 90 || e > 160);
    if (insane) atomicAdd(&cnt, 1);
    __syncthreads();
    if (threadIdx.x == 0) dflag[0] = (cnt > 64) ? 1 : 0;   // 1 => fp32 inputs/outputs
}

// ---------------- normalize x -> bf16 xb ----------------
__global__ void k_normx(const void* __restrict__ xin, const int* __restrict__ dflag,
                        u16* __restrict__ xb) {
    int i = blockIdx.x * 256 + threadIdx.x;   // handles 4 elements
    if (dflag[0]) {
        float4 v = ((const float4*)xin)[i];
        u16 o[4] = { f2bf(v.x), f2bf(v.y), f2bf(v.z), f2bf(v.w) };
        ((uint2*)xb)[i] = *(const uint2*)o;
    } else {
        ((uint2*)xb)[i] = ((const uint2*)xin)[i];
    }
}

// ---------------- gating: logits, top-2, weights (FULL PRECISION inputs) ----------------
__global__ void k_gating(const void* __restrict__ xraw, const void* __restrict__ wg,
                         const int* __restrict__ dflag, void* __restrict__ out_base,
                         int* __restrict__ te, float* __restrict__ tw) {
    int wave = threadIdx.x >> 6, lane = threadIdx.x & 63;
    int n = blockIdx.x * 4 + wave;
    int fp = dflag[0];
    float acc[8];
#pragma unroll
    for (int e = 0; e < 8; e++) acc[e] = 0.f;
    if (fp) {
        const float* xp = (const float*)xraw + (size_t)n * DDIM;
        const float* wp = (const float*)wg;
        for (int it = 0; it < 16; ++it) {
            int d = it * 64 + lane;
            float xv = xp[d];
#pragma unroll
            for (int e = 0; e < 8; e++) acc[e] += xv * wp[e * DDIM + d];
        }
    } else {
        const u16* xp = (const u16*)xraw + (size_t)n * DDIM;
        const u16* wp = (const u16*)wg;
        for (int it = 0; it < 16; ++it) {
            int d = it * 64 + lane;
            float xv = bf2f(xp[d]);
#pragma unroll
            for (int e = 0; e < 8; e++) acc[e] += xv * bf2f(wp[e * DDIM + d]);
        }
    }
#pragma unroll
    for (int e = 0; e < 8; e++) {
        for (int off = 32; off; off >>= 1) acc[e] += __shfl_xor(acc[e], off);
    }
    if (lane < 8) {
        if (fp) ((float*)out_base + (size_t)N_TOK * DDIM)[n * 8 + lane] = acc[lane];
        else    ((u16*)out_base + (size_t)N_TOK * DDIM)[n * 8 + lane] = f2bf(acc[lane]);
    }
    if (lane == 0) {
        int e0 = 0; float b0 = acc[0];
        for (int e = 1; e < 8; e++) if (acc[e] > b0) { b0 = acc[e]; e0 = e; }
        int e1 = -1; float b1 = -1e30f;
        for (int e = 0; e < 8; e++) if (e != e0 && acc[e] > b1) { b1 = acc[e]; e1 = e; }
        float m = fmaxf(b0, b1);
        float x0 = __expf(b0 - m), x1 = __expf(b1 - m);
        float s = x0 + x1;
        te[n * 2] = e0; te[n * 2 + 1] = e1;
        tw[n * 2] = x0 / s; tw[n * 2 + 1] = x1 / s;
    }
}

// ---------------- scheduling: segments + tile table + pair scatter + inverse map ----------------
__global__ void k_sched(const int* __restrict__ te, const float* __restrict__ tw,
                        int* __restrict__ pair_token, float* __restrict__ pair_weight,
                        int* __restrict__ ppos, int* __restrict__ sched) {
    __shared__ int cnt[8], cur[8];
    int t = threadIdx.x;
    if (t < 8) cnt[t] = 0;
    __syncthreads();
    for (int n = t; n < N_TOK; n += 256) {
        atomicAdd(&cnt[te[2 * n]], 1);
        atomicAdd(&cnt[te[2 * n + 1]], 1);
    }
    __syncthreads();
    if (t == 0) {
        int o = 0, mt = 0;
        for (int e = 0; e < 8; e++) {
            cur[e] = o;
            int c = cnt[e];
            for (int m0 = 0; m0 < c; m0 += 128) {
                sched[mt] = e;
                sched[MAXMT + mt] = o + m0;
                sched[2 * MAXMT + mt] = (c - m0 < 128) ? (c - m0) : 128;
                mt++;
            }
            o += c;
        }
        sched[3 * MAXMT] = mt;
        for (int i = mt; i < MAXMT; i++) { sched[i] = 0; sched[MAXMT + i] = 0; sched[2 * MAXMT + i] = 0; }
    }
    __syncthreads();
    for (int n = t; n < N_TOK; n += 256) {
#pragma unroll
        for (int s = 0; s < 2; s++) {
            int e = te[2 * n + s];
            int p = atomicAdd(&cur[e], 1);
            pair_token[p] = n;
            pair_weight[p] = tw[2 * n + s];
            ppos[2 * n + s] = p;
        }
    }
}

// ---------------- 1024x1024 transpose (flagged src dtype) -> bf16 dst ----------------
__global__ void k_transpose(const void* __restrict__ src0, const int* __restrict__ dflag,
                            u16* __restrict__ dst0) {
    int fp = dflag[0];
    int mat = blockIdx.z;
    u16* dst = dst0 + (size_t)mat * 1048576;
    __shared__ __align__(16) u16 s[64][72];
    int t = threadIdx.x;
    int r = t >> 2, seg = t & 3;
    int r0 = blockIdx.y * 64, c0 = blockIdx.x * 64;
    size_t base = (size_t)mat * 1048576 + (size_t)(r0 + r) * 1024 + c0 + seg * 16;
    u16 v[16];
    if (fp) {
        const float* sp = (const float*)src0 + base;
#pragma unroll
        for (int q = 0; q < 4; q++) {
            float4 f = ((const float4*)sp)[q];
            v[q * 4 + 0] = f2bf(f.x); v[q * 4 + 1] = f2bf(f.y);
            v[q * 4 + 2] = f2bf(f.z); v[q * 4 + 3] = f2bf(f.w);
        }
    } else {
        const u16* sp = (const u16*)src0 + base;
        *(uint4*)&v[0] = *(const uint4*)sp;
        *(uint4*)&v[8] = *(const uint4*)(sp + 8);
    }
    *(uint4*)&s[r][seg * 16] = *(const uint4*)&v[0];
    *(uint4*)&s[r][seg * 16 + 8] = *(const uint4*)&v[8];
    __syncthreads();
    u16 tmp[16];
#pragma unroll
    for (int j = 0; j < 16; j++) tmp[j] = s[seg * 16 + j][r];
    u16* dp = dst + (size_t)(c0 + r) * 1024 + r0 + seg * 16;
    *(uint4*)dp = *(const uint4*)&tmp[0];
    *(uint4*)(dp + 8) = *(const uint4*)&tmp[8];
}

// ---------------- grouped GEMM: 128 pairs x 64 cols, BK=64, register staging ----------------
// MODE 0: Obuf = Asrc(gathered x) @ wt          (H pass)
// MODE 1: Obuf = silu(Obuf) * (Asrc @ wt)       (U pass, in-place combine)
// MODE 2: Obuf = Asrc(pair rows) @ wt           (Y pass)
template <int MODE>
__launch_bounds__(256, 2)
__global__ void k_gemm(const u16* __restrict__ Asrc, const u16* __restrict__ wt,
                       const int* __restrict__ pair_token, const int* __restrict__ sched,
                       u16* __restrict__ Obuf) {
    int bn = blockIdx.x;
    int bm = blockIdx.y;
    int total = sched[3 * MAXMT];
    if (bm >= total) return;
    int e = sched[bm];
    int row0 = sched[MAXMT + bm];
    int rowsv = sched[2 * MAXMT + bm];

    __shared__ __align__(16) u16 sA[128 * 72];
    __shared__ __align__(16) u16 sB[64 * 72];

    int tid = threadIdx.x;
    int wave = tid >> 6, lane = tid & 63;
    int wm = wave & 1, wn = wave >> 1;
    int quad = lane >> 4, l15 = lane & 15;

    const u16* aPtr[4]; int aOff[4];
#pragma unroll
    for (int c = 0; c < 4; c++) {
        int q = c * 256 + tid, row = q >> 3, slot = q & 7;
        int cr = row < rowsv ? row : 0;
        const u16* src;
        if (MODE == 2) src = Asrc + (size_t)(row0 + cr) * 1024;
        else           src = Asrc + (size_t)pair_token[row0 + cr] * 1024;
        aPtr[c] = src + slot * 8;
        aOff[c] = row * 72 + slot * 8;
    }
    const u16* bPtr[2]; int bOff[2];
#pragma unroll
    for (int c = 0; c < 2; c++) {
        int q = c * 256 + tid, row = q >> 3, slot = q & 7;
        bPtr[c] = wt + ((size_t)e * 1024 + bn * 64 + row) * 1024 + slot * 8;
        bOff[c] = row * 72 + slot * 8;
    }

    f32x4 acc[4][2];
#pragma unroll
    for (int i = 0; i < 4; i++)
#pragma unroll
        for (int j = 0; j < 2; j++) acc[i][j] = (f32x4)0.f;

    for (int kt = 0; kt < 16; ++kt) {
        int k0 = kt * 64;
        uint4 va[4], vb[2];
#pragma unroll
        for (int c = 0; c < 4; c++) va[c] = *(const uint4*)(aPtr[c] + k0);
#pragma unroll
        for (int c = 0; c < 2; c++) vb[c] = *(const uint4*)(bPtr[c] + k0);
        __syncthreads();
#pragma unroll
        for (int c = 0; c < 4; c++) *(uint4*)&sA[aOff[c]] = va[c];
#pragma unroll
        for (int c = 0; c < 2; c++) *(uint4*)&sB[bOff[c]] = vb[c];
        __syncthreads();
#pragma unroll
        for (int kk = 0; kk < 2; ++kk) {
            bf16x8 a[4], b[2];
#pragma unroll
            for (int i = 0; i < 4; i++) {
                int m = wm * 64 + i * 16 + l15;
                a[i] = *(const bf16x8*)&sA[m * 72 + (kk * 4 + quad) * 8];
            }
#pragma unroll
            for (int j = 0; j < 2; j++) {
                int nn = wn * 32 + j * 16 + l15;
                b[j] = *(const bf16x8*)&sB[nn * 72 + (kk * 4 + quad) * 8];
            }
#pragma unroll
            for (int i = 0; i < 4; i++)
#pragma unroll
                for (int j = 0; j < 2; j++)
                    acc[i][j] = __builtin_amdgcn_mfma_f32_16x16x32_bf16(a[i], b[j], acc[i][j], 0, 0, 0);
        }
    }
#pragma unroll
    for (int i = 0; i < 4; i++)
#pragma unroll
        for (int j = 0; j < 2; j++)
#pragma unroll
            for (int r = 0; r < 4; r++) {
                int lr = wm * 64 + i * 16 + quad * 4 + r;
                if (lr < rowsv) {
                    int col = bn * 64 + wn * 32 + j * 16 + l15;
                    size_t idx = (size_t)(row0 + lr) * 1024 + col;
                    float v = acc[i][j][r];
                    if (MODE == 1) {
                        float h = bf2f(Obuf[idx]);           // Obuf holds H
                        v = h * v / (1.0f + __expf(-h));     // silu(h)*u
                    }
                    Obuf[idx] = f2bf(v);
                }
            }
}

// ---------------- combine: out[n] = w0*Y[p0] + w1*Y[p1] ----------------
__global__ void k_combine(const u16* __restrict__ Y, const int* __restrict__ ppos,
                          const float* __restrict__ pwt, const int* __restrict__ dflag,
                          void* __restrict__ out) {
    int n = blockIdx.x, t = threadIdx.x;
    int p0 = ppos[2 * n], p1 = ppos[2 * n + 1];
    float w0 = pwt[p0], w1 = pwt[p1];
    uint2 a = *(const uint2*)(Y + (size_t)p0 * 1024 + t * 4);
    uint2 b = *(const uint2*)(Y + (size_t)p1 * 1024 + t * 4);
    const u16* ap = (const u16*)&a;
    const u16* bp = (const u16*)&b;
    float r[4];
#pragma unroll
    for (int j = 0; j < 4; j++) r[j] = w0 * bf2f(ap[j]) + w1 * bf2f(bp[j]);
    if (dflag[0]) {
        float4 o = { r[0], r[1], r[2], r[3] };
        *(float4*)((float*)out + (size_t)n * 1024 + t * 4) = o;
    } else {
        u16 o[4] = { f2bf(r[0]), f2bf(r[1]), f2bf(r[2]), f2bf(r[3]) };
        *(uint2*)((u16*)out + (size_t)n * 1024 + t * 4) = *(const uint2*)o;
    }
}

extern "C" void kernel_launch(void* const* d_in, const int* in_sizes, int n_in,
                              void* d_out, int out_size, void* d_ws, size_t ws_size,
                              hipStream_t stream) {
    const void* x  = d_in[0];
    const void* wg = d_in[1];
    const void* w1 = d_in[2];
    const void* w3 = d_in[3];
    const void* w2 = d_in[4];

    u16* wt    = (u16*)d_ws;                 // 16 MB, serially reused for w1t/w3t/w2t
    u16* Hbuf  = wt + (size_t)8 * 1048576;   // 8 MB (H, then silu(H)*U in place)
    u16* Ybuf  = Hbuf + (size_t)4096 * 1024; // 8 MB
    u16* xb    = Ybuf + (size_t)4096 * 1024; // 4 MB normalized bf16 x
    int*   te   = (int*)(xb + (size_t)N_TOK * DDIM);
    float* tw   = (float*)(te + 2 * N_TOK);
    int*   ptok = (int*)(tw + 2 * N_TOK);
    float* pwt  = (float*)(ptok + 2 * N_TOK);
    int*   ppos = (int*)(pwt + 2 * N_TOK);
    int*   sched = ppos + 2 * N_TOK;
    int*   dflag = sched + 128;

    k_detect<<<1, 512, 0, stream>>>((const u16*)x, dflag);
    k_normx<<<2048, 256, 0, stream>>>(x, dflag, xb);
    k_gating<<<512, 256, 0, stream>>>(x, wg, dflag, d_out, te, tw);
    k_sched<<<1, 256, 0, stream>>>(te, tw, ptok, pwt, ppos, sched);

    k_transpose<<<dim3(16, 16, 8), 256, 0, stream>>>(w1, dflag, wt);
    k_gemm<0><<<dim3(16, MAXMT), 256, 0, stream>>>(xb, wt, ptok, sched, Hbuf);
    k_transpose<<<dim3(16, 16, 8), 256, 0, stream>>>(w3, dflag, wt);
    k_gemm<1><<<dim3(16, MAXMT), 256, 0, stream>>>(xb, wt, ptok, sched, Hbuf);
    k_transpose<<<dim3(16, 16, 8), 256, 0, stream>>>(w2, dflag, wt);
    k_gemm<2><<<dim3(16, MAXMT), 256, 0, stream>>>(Hbuf, wt, ptok, sched, Ybuf);

    k_combine<<<2048, 256, 0, stream>>>(Ybuf, ppos, pwt, dflag, d_out);
}

// Round 4
// 432.340 us; speedup vs baseline: 1.0111x; 1.0111x over previous
//
#include <hip/hip_runtime.h>
#include <stdint.h>

typedef unsigned short u16;
typedef __attribute__((ext_vector_type(8))) __bf16 bf16x8;
typedef __attribute__((ext_vector_type(4))) float f32x4;

#define MAXMT 40
#define N_TOK 2048
#define DDIM 1024
#define FDIM 1024

#define DEV static __device__ __forceinline__

DEV float bf2f(u16 u) {
    union { uint32_t i; float f; } v;
    v.i = ((uint32_t)u) << 16;
    return v.f;
}
DEV u16 f2bf(float f) {
    union { float f; uint32_t i; } v;
    v.f = f;
    uint32_t x = v.i;
    return (u16)((x + 0x7fffu + ((x >> 16) & 1u)) >> 16);  // RNE
}

// ---------------- dtype detection: bf16 stream vs fp32-reinterpreted ----------------
__global__ void k_detect(const u16* __restrict__ xr, int* __restrict__ dflag) {
    __shared__ int cnt;
    if (threadIdx.x == 0) cnt = 0;
    __syncthreads();
    u16 u = xr[threadIdx.x];            // 512 samples
    int e = (u >> 7) & 0xff;
    int insane = (e != 0) && (e < 90 || e > 160);
    if (insane) atomicAdd(&cnt, 1);
    __syncthreads();
    if (threadIdx.x == 0) dflag[0] = (cnt > 64) ? 1 : 0;   // 1 => fp32 inputs/outputs
}

// ---------------- normalize x -> bf16 xb ----------------
__global__ void k_normx(const void* __restrict__ xin, const int* __restrict__ dflag,
                        u16* __restrict__ xb) {
    int i = blockIdx.x * 256 + threadIdx.x;   // handles 4 elements
    if (dflag[0]) {
        float4 v = ((const float4*)xin)[i];
        u16 o[4] = { f2bf(v.x), f2bf(v.y), f2bf(v.z), f2bf(v.w) };
        ((uint2*)xb)[i] = *(const uint2*)o;
    } else {
        ((uint2*)xb)[i] = ((const uint2*)xin)[i];
    }
}

// ---------------- gating: logits, top-2, weights (FULL PRECISION inputs) ----------------
__global__ void k_gating(const void* __restrict__ xraw, const void* __restrict__ wg,
                         const int* __restrict__ dflag, void* __restrict__ out_base,
                         int* __restrict__ te, float* __restrict__ tw) {
    int wave = threadIdx.x >> 6, lane = threadIdx.x & 63;
    int n = blockIdx.x * 4 + wave;
    int fp = dflag[0];
    float acc[8];
#pragma unroll
    for (int e = 0; e < 8; e++) acc[e] = 0.f;
    if (fp) {
        const float* xp = (const float*)xraw + (size_t)n * DDIM;
        const float* wp = (const float*)wg;
        for (int it = 0; it < 16; ++it) {
            int d = it * 64 + lane;
            float xv = xp[d];
#pragma unroll
            for (int e = 0; e < 8; e++) acc[e] += xv * wp[e * DDIM + d];
        }
    } else {
        const u16* xp = (const u16*)xraw + (size_t)n * DDIM;
        const u16* wp = (const u16*)wg;
        for (int it = 0; it < 16; ++it) {
            int d = it * 64 + lane;
            float xv = bf2f(xp[d]);
#pragma unroll
            for (int e = 0; e < 8; e++) acc[e] += xv * bf2f(wp[e * DDIM + d]);
        }
    }
#pragma unroll
    for (int e = 0; e < 8; e++) {
        for (int off = 32; off; off >>= 1) acc[e] += __shfl_xor(acc[e], off);
    }
    if (lane < 8) {
        if (fp) ((float*)out_base + (size_t)N_TOK * DDIM)[n * 8 + lane] = acc[lane];
        else    ((u16*)out_base + (size_t)N_TOK * DDIM)[n * 8 + lane] = f2bf(acc[lane]);
    }
    if (lane == 0) {
        int e0 = 0; float b0 = acc[0];
        for (int e = 1; e < 8; e++) if (acc[e] > b0) { b0 = acc[e]; e0 = e; }
        int e1 = -1; float b1 = -1e30f;
        for (int e = 0; e < 8; e++) if (e != e0 && acc[e] > b1) { b1 = acc[e]; e1 = e; }
        float m = fmaxf(b0, b1);
        float x0 = __expf(b0 - m), x1 = __expf(b1 - m);
        float s = x0 + x1;
        te[n * 2] = e0; te[n * 2 + 1] = e1;
        tw[n * 2] = x0 / s; tw[n * 2 + 1] = x1 / s;
    }
}

// ---------------- scheduling: segments + tile table (128-row tiles) + pair scatter ----------------
__global__ void k_sched(const int* __restrict__ te, const float* __restrict__ tw,
                        int* __restrict__ pair_token, float* __restrict__ pair_weight,
                        int* __restrict__ ppos, int* __restrict__ sched) {
    __shared__ int cnt[8], cur[8];
    int t = threadIdx.x;
    if (t < 8) cnt[t] = 0;
    __syncthreads();
    for (int n = t; n < N_TOK; n += 256) {
        atomicAdd(&cnt[te[2 * n]], 1);
        atomicAdd(&cnt[te[2 * n + 1]], 1);
    }
    __syncthreads();
    if (t == 0) {
        int o = 0, mt = 0;
        for (int e = 0; e < 8; e++) {
            cur[e] = o;
            int c = cnt[e];
            for (int m0 = 0; m0 < c; m0 += 128) {
                sched[mt] = e;
                sched[MAXMT + mt] = o + m0;
                sched[2 * MAXMT + mt] = (c - m0 < 128) ? (c - m0) : 128;
                mt++;
            }
            o += c;
        }
        sched[3 * MAXMT] = mt;
        for (int i = mt; i < MAXMT; i++) { sched[i] = 0; sched[MAXMT + i] = 0; sched[2 * MAXMT + i] = 0; }
    }
    __syncthreads();
    for (int n = t; n < N_TOK; n += 256) {
#pragma unroll
        for (int s = 0; s < 2; s++) {
            int e = te[2 * n + s];
            int p = atomicAdd(&cur[e], 1);
            pair_token[p] = n;
            pair_weight[p] = tw[2 * n + s];
            ppos[2 * n + s] = p;
        }
    }
}

// ---------------- 1024x1024 transpose (flagged src dtype) -> bf16 dst ----------------
__global__ void k_transpose(const void* __restrict__ src0, const int* __restrict__ dflag,
                            u16* __restrict__ dst0) {
    int fp = dflag[0];
    int mat = blockIdx.z;
    u16* dst = dst0 + (size_t)mat * 1048576;
    __shared__ __align__(16) u16 s[64][72];
    int t = threadIdx.x;
    int r = t >> 2, seg = t & 3;
    int r0 = blockIdx.y * 64, c0 = blockIdx.x * 64;
    size_t base = (size_t)mat * 1048576 + (size_t)(r0 + r) * 1024 + c0 + seg * 16;
    u16 v[16];
    if (fp) {
        const float* sp = (const float*)src0 + base;
#pragma unroll
        for (int q = 0; q < 4; q++) {
            float4 f = ((const float4*)sp)[q];
            v[q * 4 + 0] = f2bf(f.x); v[q * 4 + 1] = f2bf(f.y);
            v[q * 4 + 2] = f2bf(f.z); v[q * 4 + 3] = f2bf(f.w);
        }
    } else {
        const u16* sp = (const u16*)src0 + base;
        *(uint4*)&v[0] = *(const uint4*)sp;
        *(uint4*)&v[8] = *(const uint4*)(sp + 8);
    }
    *(uint4*)&s[r][seg * 16] = *(const uint4*)&v[0];
    *(uint4*)&s[r][seg * 16 + 8] = *(const uint4*)&v[8];
    __syncthreads();
    u16 tmp[16];
#pragma unroll
    for (int j = 0; j < 16; j++) tmp[j] = s[seg * 16 + j][r];
    u16* dp = dst + (size_t)(c0 + r) * 1024 + r0 + seg * 16;
    *(uint4*)dp = *(const uint4*)&tmp[0];
    *(uint4*)(dp + 8) = *(const uint4*)&tmp[8];
}

// ---------------- grouped GEMM: 128 pairs x 128 cols, BK=64, pipelined register prefetch ----------------
// MODE 0: Obuf = Asrc(gathered x) @ wt          (H pass)
// MODE 1: Obuf = silu(Obuf) * (Asrc @ wt)       (U pass, in-place combine)
// MODE 2: Obuf = Asrc(pair rows) @ wt           (Y pass)
template <int MODE>
__launch_bounds__(256, 2)
__global__ void k_gemm(const u16* __restrict__ Asrc, const u16* __restrict__ wt,
                       const int* __restrict__ pair_token, const int* __restrict__ sched,
                       u16* __restrict__ Obuf) {
    int bn = blockIdx.x;          // 8 tiles of 128 cols
    int bm = blockIdx.y;
    int total = sched[3 * MAXMT];
    if (bm >= total) return;
    int e = sched[bm];
    int row0 = sched[MAXMT + bm];
    int rowsv = sched[2 * MAXMT + bm];

    __shared__ __align__(16) u16 sA[128 * 72];   // 18 KB, stride 72 (2-way reads, measured-cheap)
    __shared__ __align__(16) u16 sB[128 * 72];   // 18 KB

    int tid = threadIdx.x;
    int wave = tid >> 6, lane = tid & 63;
    int wm = wave & 1, wn = wave >> 1;           // wave computes 64x64 of the 128x128 tile
    int quad = lane >> 4, l15 = lane & 15;

    // staging map: 4 chunks each for A and B; chunk p = c*256+tid -> (row = p>>3, slot = p&7)
    const u16* aPtr[4]; int aOff[4];
#pragma unroll
    for (int c = 0; c < 4; c++) {
        int p = c * 256 + tid, row = p >> 3, slot = p & 7;
        int cr = row < rowsv ? row : 0;
        const u16* src;
        if (MODE == 2) src = Asrc + (size_t)(row0 + cr) * 1024;
        else           src = Asrc + (size_t)pair_token[row0 + cr] * 1024;
        aPtr[c] = src + slot * 8;
        aOff[c] = row * 72 + slot * 8;
    }
    const u16* bPtr[4]; int bOff[4];
#pragma unroll
    for (int c = 0; c < 4; c++) {
        int p = c * 256 + tid, row = p >> 3, slot = p & 7;
        bPtr[c] = wt + ((size_t)e * 1024 + bn * 128 + row) * 1024 + slot * 8;
        bOff[c] = row * 72 + slot * 8;
    }

    f32x4 acc[4][4];
#pragma unroll
    for (int i = 0; i < 4; i++)
#pragma unroll
        for (int j = 0; j < 4; j++) acc[i][j] = (f32x4)0.f;

    uint4 va[4], vb[4];
    // prefetch kt=0
#pragma unroll
    for (int c = 0; c < 4; c++) va[c] = *(const uint4*)(aPtr[c]);
#pragma unroll
    for (int c = 0; c < 4; c++) vb[c] = *(const uint4*)(bPtr[c]);

    for (int kt = 0; kt < 16; ++kt) {
        __syncthreads();                          // prior LDS reads done
#pragma unroll
        for (int c = 0; c < 4; c++) *(uint4*)&sA[aOff[c]] = va[c];
#pragma unroll
        for (int c = 0; c < 4; c++) *(uint4*)&sB[bOff[c]] = vb[c];
        __syncthreads();
        // issue next tile's loads BEFORE compute -> latency hides under MFMA phase
        if (kt < 15) {
            int k1 = (kt + 1) * 64;
#pragma unroll
            for (int c = 0; c < 4; c++) va[c] = *(const uint4*)(aPtr[c] + k1);
#pragma unroll
            for (int c = 0; c < 4; c++) vb[c] = *(const uint4*)(bPtr[c] + k1);
        }
#pragma unroll
        for (int kk = 0; kk < 2; ++kk) {
            bf16x8 a[4], b[4];
#pragma unroll
            for (int i = 0; i < 4; i++) {
                int m = wm * 64 + i * 16 + l15;
                a[i] = *(const bf16x8*)&sA[m * 72 + (kk * 4 + quad) * 8];
            }
#pragma unroll
            for (int j = 0; j < 4; j++) {
                int nn = wn * 64 + j * 16 + l15;
                b[j] = *(const bf16x8*)&sB[nn * 72 + (kk * 4 + quad) * 8];
            }
#pragma unroll
            for (int i = 0; i < 4; i++)
#pragma unroll
                for (int j = 0; j < 4; j++)
                    acc[i][j] = __builtin_amdgcn_mfma_f32_16x16x32_bf16(a[i], b[j], acc[i][j], 0, 0, 0);
        }
    }
#pragma unroll
    for (int i = 0; i < 4; i++)
#pragma unroll
        for (int j = 0; j < 4; j++)
#pragma unroll
            for (int r = 0; r < 4; r++) {
                int lr = wm * 64 + i * 16 + quad * 4 + r;
                if (lr < rowsv) {
                    int col = bn * 128 + wn * 64 + j * 16 + l15;
                    size_t idx = (size_t)(row0 + lr) * 1024 + col;
                    float v = acc[i][j][r];
                    if (MODE == 1) {
                        float h = bf2f(Obuf[idx]);           // Obuf holds H
                        v = h * v / (1.0f + __expf(-h));     // silu(h)*u
                    }
                    Obuf[idx] = f2bf(v);
                }
            }
}

// ---------------- combine: out[n] = w0*Y[p0] + w1*Y[p1] ----------------
__global__ void k_combine(const u16* __restrict__ Y, const int* __restrict__ ppos,
                          const float* __restrict__ pwt, const int* __restrict__ dflag,
                          void* __restrict__ out) {
    int n = blockIdx.x, t = threadIdx.x;
    int p0 = ppos[2 * n], p1 = ppos[2 * n + 1];
    float w0 = pwt[p0], w1 = pwt[p1];
    uint2 a = *(const uint2*)(Y + (size_t)p0 * 1024 + t * 4);
    uint2 b = *(const uint2*)(Y + (size_t)p1 * 1024 + t * 4);
    const u16* ap = (const u16*)&a;
    const u16* bp = (const u16*)&b;
    float r[4];
#pragma unroll
    for (int j = 0; j < 4; j++) r[j] = w0 * bf2f(ap[j]) + w1 * bf2f(bp[j]);
    if (dflag[0]) {
        float4 o = { r[0], r[1], r[2], r[3] };
        *(float4*)((float*)out + (size_t)n * 1024 + t * 4) = o;
    } else {
        u16 o[4] = { f2bf(r[0]), f2bf(r[1]), f2bf(r[2]), f2bf(r[3]) };
        *(uint2*)((u16*)out + (size_t)n * 1024 + t * 4) = *(const uint2*)o;
    }
}

extern "C" void kernel_launch(void* const* d_in, const int* in_sizes, int n_in,
                              void* d_out, int out_size, void* d_ws, size_t ws_size,
                              hipStream_t stream) {
    const void* x  = d_in[0];
    const void* wg = d_in[1];
    const void* w1 = d_in[2];
    const void* w3 = d_in[3];
    const void* w2 = d_in[4];

    u16* wt    = (u16*)d_ws;                 // 16 MB, serially reused for w1t/w3t/w2t
    u16* Hbuf  = wt + (size_t)8 * 1048576;   // 8 MB (H, then silu(H)*U in place)
    u16* Ybuf  = Hbuf + (size_t)4096 * 1024; // 8 MB
    u16* xb    = Ybuf + (size_t)4096 * 1024; // 4 MB normalized bf16 x
    int*   te   = (int*)(xb + (size_t)N_TOK * DDIM);
    float* tw   = (float*)(te + 2 * N_TOK);
    int*   ptok = (int*)(tw + 2 * N_TOK);
    float* pwt  = (float*)(ptok + 2 * N_TOK);
    int*   ppos = (int*)(pwt + 2 * N_TOK);
    int*   sched = ppos + 2 * N_TOK;
    int*   dflag = sched + 128;

    k_detect<<<1, 512, 0, stream>>>((const u16*)x, dflag);
    k_normx<<<2048, 256, 0, stream>>>(x, dflag, xb);
    k_gating<<<512, 256, 0, stream>>>(x, wg, dflag, d_out, te, tw);
    k_sched<<<1, 256, 0, stream>>>(te, tw, ptok, pwt, ppos, sched);

    k_transpose<<<dim3(16, 16, 8), 256, 0, stream>>>(w1, dflag, wt);
    k_gemm<0><<<dim3(8, MAXMT), 256, 0, stream>>>(xb, wt, ptok, sched, Hbuf);
    k_transpose<<<dim3(16, 16, 8), 256, 0, stream>>>(w3, dflag, wt);
    k_gemm<1><<<dim3(8, MAXMT), 256, 0, stream>>>(xb, wt, ptok, sched, Hbuf);
    k_transpose<<<dim3(16, 16, 8), 256, 0, stream>>>(w2, dflag, wt);
    k_gemm<2><<<dim3(8, MAXMT), 256, 0, stream>>>(Hbuf, wt, ptok, sched, Ybuf);

    k_combine<<<2048, 256, 0, stream>>>(Ybuf, ppos, pwt, dflag, d_out);
}

// Round 5
// 228.174 us; speedup vs baseline: 1.9158x; 1.8948x over previous
//
#include <hip/hip_runtime.h>
#include <stdint.h>

typedef unsigned short u16;
typedef __attribute__((ext_vector_type(8))) __bf16 bf16x8;
typedef __attribute__((ext_vector_type(4))) float f32x4;

#define MAXMT 40
#define N_TOK 2048
#define DDIM 1024
#define FDIM 1024

#define DEV static __device__ __forceinline__

DEV float bf2f(u16 u) {
    union { uint32_t i; float f; } v;
    v.i = ((uint32_t)u) << 16;
    return v.f;
}
DEV u16 f2bf(float f) {
    union { float f; uint32_t i; } v;
    v.f = f;
    uint32_t x = v.i;
    return (u16)((x + 0x7fffu + ((x >> 16) & 1u)) >> 16);  // RNE
}

// async global->LDS, 16B per lane; lds base wave-uniform, HW writes lane i at base+16*i
DEV void async_copy16(const u16* gsrc, u16* ldst) {
    __builtin_amdgcn_global_load_lds(
        (const __attribute__((address_space(1))) void*)(uintptr_t)gsrc,
        (__attribute__((address_space(3))) void*)(uint32_t)(uintptr_t)ldst,
        16, 0, 0);
}

// ---------------- dtype detection ----------------
__global__ void k_detect(const u16* __restrict__ xr, int* __restrict__ dflag) {
    __shared__ int cnt;
    if (threadIdx.x == 0) cnt = 0;
    __syncthreads();
    u16 u = xr[threadIdx.x];
    int e = (u >> 7) & 0xff;
    int insane = (e != 0) && (e < 90 || e > 160);
    if (insane) atomicAdd(&cnt, 1);
    __syncthreads();
    if (threadIdx.x == 0) dflag[0] = (cnt > 64) ? 1 : 0;   // 1 => fp32 inputs/outputs
}

// ---------------- normalize x -> bf16 xb ----------------
__global__ void k_normx(const void* __restrict__ xin, const int* __restrict__ dflag,
                        u16* __restrict__ xb) {
    int i = blockIdx.x * 256 + threadIdx.x;
    if (dflag[0]) {
        float4 v = ((const float4*)xin)[i];
        u16 o[4] = { f2bf(v.x), f2bf(v.y), f2bf(v.z), f2bf(v.w) };
        ((uint2*)xb)[i] = *(const uint2*)o;
    } else {
        ((uint2*)xb)[i] = ((const uint2*)xin)[i];
    }
}

// ---------------- gating: logits, top-2, weights (full-precision inputs) ----------------
__global__ void k_gating(const void* __restrict__ xraw, const void* __restrict__ wg,
                         const int* __restrict__ dflag, void* __restrict__ out_base,
                         int* __restrict__ te, float* __restrict__ tw) {
    int wave = threadIdx.x >> 6, lane = threadIdx.x & 63;
    int n = blockIdx.x * 4 + wave;
    int fp = dflag[0];
    float acc[8];
#pragma unroll
    for (int e = 0; e < 8; e++) acc[e] = 0.f;
    if (fp) {
        const float* xp = (const float*)xraw + (size_t)n * DDIM;
        const float* wp = (const float*)wg;
        for (int it = 0; it < 16; ++it) {
            int d = it * 64 + lane;
            float xv = xp[d];
#pragma unroll
            for (int e = 0; e < 8; e++) acc[e] += xv * wp[e * DDIM + d];
        }
    } else {
        const u16* xp = (const u16*)xraw + (size_t)n * DDIM;
        const u16* wp = (const u16*)wg;
        for (int it = 0; it < 16; ++it) {
            int d = it * 64 + lane;
            float xv = bf2f(xp[d]);
#pragma unroll
            for (int e = 0; e < 8; e++) acc[e] += xv * bf2f(wp[e * DDIM + d]);
        }
    }
#pragma unroll
    for (int e = 0; e < 8; e++) {
        for (int off = 32; off; off >>= 1) acc[e] += __shfl_xor(acc[e], off);
    }
    if (lane < 8) {
        if (fp) ((float*)out_base + (size_t)N_TOK * DDIM)[n * 8 + lane] = acc[lane];
        else    ((u16*)out_base + (size_t)N_TOK * DDIM)[n * 8 + lane] = f2bf(acc[lane]);
    }
    if (lane == 0) {
        int e0 = 0; float b0 = acc[0];
        for (int e = 1; e < 8; e++) if (acc[e] > b0) { b0 = acc[e]; e0 = e; }
        int e1 = -1; float b1 = -1e30f;
        for (int e = 0; e < 8; e++) if (e != e0 && acc[e] > b1) { b1 = acc[e]; e1 = e; }
        float m = fmaxf(b0, b1);
        float x0 = __expf(b0 - m), x1 = __expf(b1 - m);
        float s = x0 + x1;
        te[n * 2] = e0; te[n * 2 + 1] = e1;
        tw[n * 2] = x0 / s; tw[n * 2 + 1] = x1 / s;
    }
}

// ---------------- scheduling ----------------
__global__ void k_sched(const int* __restrict__ te, const float* __restrict__ tw,
                        int* __restrict__ pair_token, float* __restrict__ pair_weight,
                        int* __restrict__ ppos, int* __restrict__ sched) {
    __shared__ int cnt[8], cur[8];
    int t = threadIdx.x;
    if (t < 8) cnt[t] = 0;
    __syncthreads();
    for (int n = t; n < N_TOK; n += 256) {
        atomicAdd(&cnt[te[2 * n]], 1);
        atomicAdd(&cnt[te[2 * n + 1]], 1);
    }
    __syncthreads();
    if (t == 0) {
        int o = 0, mt = 0;
        for (int e = 0; e < 8; e++) {
            cur[e] = o;
            int c = cnt[e];
            for (int m0 = 0; m0 < c; m0 += 128) {
                sched[mt] = e;
                sched[MAXMT + mt] = o + m0;
                sched[2 * MAXMT + mt] = (c - m0 < 128) ? (c - m0) : 128;
                mt++;
            }
            o += c;
        }
        sched[3 * MAXMT] = mt;
        for (int i = mt; i < MAXMT; i++) { sched[i] = 0; sched[MAXMT + i] = 0; sched[2 * MAXMT + i] = 0; }
    }
    __syncthreads();
    for (int n = t; n < N_TOK; n += 256) {
#pragma unroll
        for (int s = 0; s < 2; s++) {
            int e = te[2 * n + s];
            int p = atomicAdd(&cur[e], 1);
            pair_token[p] = n;
            pair_weight[p] = tw[2 * n + s];
            ppos[2 * n + s] = p;
        }
    }
}

// ---------------- 1024x1024 transpose (flagged src dtype) -> bf16 dst ----------------
__global__ void k_transpose(const void* __restrict__ src0, const int* __restrict__ dflag,
                            u16* __restrict__ dst0) {
    int fp = dflag[0];
    int mat = blockIdx.z;
    u16* dst = dst0 + (size_t)mat * 1048576;
    __shared__ __align__(16) u16 s[64][72];
    int t = threadIdx.x;
    int r = t >> 2, seg = t & 3;
    int r0 = blockIdx.y * 64, c0 = blockIdx.x * 64;
    size_t base = (size_t)mat * 1048576 + (size_t)(r0 + r) * 1024 + c0 + seg * 16;
    u16 v[16];
    if (fp) {
        const float* sp = (const float*)src0 + base;
#pragma unroll
        for (int q = 0; q < 4; q++) {
            float4 f = ((const float4*)sp)[q];
            v[q * 4 + 0] = f2bf(f.x); v[q * 4 + 1] = f2bf(f.y);
            v[q * 4 + 2] = f2bf(f.z); v[q * 4 + 3] = f2bf(f.w);
        }
    } else {
        const u16* sp = (const u16*)src0 + base;
        *(uint4*)&v[0] = *(const uint4*)sp;
        *(uint4*)&v[8] = *(const uint4*)(sp + 8);
    }
    *(uint4*)&s[r][seg * 16] = *(const uint4*)&v[0];
    *(uint4*)&s[r][seg * 16 + 8] = *(const uint4*)&v[8];
    __syncthreads();
    u16 tmp[16];
#pragma unroll
    for (int j = 0; j < 16; j++) tmp[j] = s[seg * 16 + j][r];
    u16* dp = dst + (size_t)(c0 + r) * 1024 + r0 + seg * 16;
    *(uint4*)dp = *(const uint4*)&tmp[0];
    *(uint4*)(dp + 8) = *(const uint4*)&tmp[8];
}

// ===================== fused SwiGLU GEMM: Abuf = silu(X@W1) * (X@W3) =====================
// m97 structure: global_load_lds width-16, XOR-swizzled linear LDS, 2-barrier K-loop.
// Tile: 128 pairs x 128 f-cols, BK=64. LDS: sA 16K + sB1 16K + sB3 16K = 48 KB.
__launch_bounds__(256, 2)
__global__ void k_gemm13(const u16* __restrict__ xb, const u16* __restrict__ w1t,
                         const u16* __restrict__ w3t, const int* __restrict__ pair_token,
                         const int* __restrict__ sched, u16* __restrict__ Abuf) {
    __shared__ __align__(16) u16 smem[24576];     // 48 KB
    u16* sA  = smem;                              // 128x64
    u16* sB1 = smem + 8192;                       // 128x64
    u16* sB3 = smem + 16384;                      // 128x64

    int bn = blockIdx.x;          // 8 tiles of 128 cols
    int bm = blockIdx.y;
    int total = sched[3 * MAXMT];
    if (bm >= total) return;
    int e = sched[bm];
    int row0 = sched[MAXMT + bm];
    int rowsv = sched[2 * MAXMT + bm];

    int tid = threadIdx.x;
    int wave = tid >> 6, lane = tid & 63;
    int wm = wave & 1, wn = wave >> 1;
    int quad = lane >> 4, l15 = lane & 15;
    int lsub = lane >> 3, slot = lane & 7;

    // staging: chunk c covers rows c*32 + wave*8 + lsub; LDS linear, global k-chunk XOR-swizzled
    const u16* gA[4]; u16* lA[4];
    const u16* gB1[4]; const u16* gB3[4]; u16* lB[4];
#pragma unroll
    for (int c = 0; c < 4; c++) {
        int row = c * 32 + wave * 8 + lsub;
        int cr = row < rowsv ? row : 0;
        int tok = pair_token[row0 + cr];
        int gch = slot ^ (row & 7);
        gA[c] = xb + (size_t)tok * DDIM + gch * 8;
        int fcol = bn * 128 + row;
        gB1[c] = w1t + ((size_t)e * 1024 + fcol) * 1024 + gch * 8;
        gB3[c] = w3t + ((size_t)e * 1024 + fcol) * 1024 + gch * 8;
        lA[c] = sA + c * 2048 + wave * 512;       // + lane*8 implicit (HW)
        lB[c] = (u16*)(uintptr_t)(c * 2048 + wave * 512);  // offset reused for B1/B3
    }

    f32x4 acc_h[4][4], acc_u[4][4];
#pragma unroll
    for (int i = 0; i < 4; i++)
#pragma unroll
        for (int j = 0; j < 4; j++) { acc_h[i][j] = (f32x4)0.f; acc_u[i][j] = (f32x4)0.f; }

    for (int kt = 0; kt < 16; ++kt) {
        int k0 = kt * 64;
        __syncthreads();
#pragma unroll
        for (int c = 0; c < 4; c++) {
            size_t off = (size_t)(uintptr_t)lB[c];
            async_copy16(gA[c] + k0, lA[c]);
            async_copy16(gB1[c] + k0, sB1 + off);
            async_copy16(gB3[c] + k0, sB3 + off);
        }
        __syncthreads();
#pragma unroll
        for (int kk = 0; kk < 2; ++kk) {
            bf16x8 a[4], b1[4], b3[4];
#pragma unroll
            for (int i = 0; i < 4; i++) {
                int m = wm * 64 + i * 16 + l15;
                int s = (kk * 4 + quad) ^ (m & 7);
                a[i] = *(const bf16x8*)&sA[m * 64 + s * 8];
            }
#pragma unroll
            for (int j = 0; j < 4; j++) {
                int nn = wn * 64 + j * 16 + l15;
                int s = (kk * 4 + quad) ^ (nn & 7);
                b1[j] = *(const bf16x8*)&sB1[nn * 64 + s * 8];
                b3[j] = *(const bf16x8*)&sB3[nn * 64 + s * 8];
            }
#pragma unroll
            for (int i = 0; i < 4; i++)
#pragma unroll
                for (int j = 0; j < 4; j++) {
                    acc_h[i][j] = __builtin_amdgcn_mfma_f32_16x16x32_bf16(a[i], b1[j], acc_h[i][j], 0, 0, 0);
                    acc_u[i][j] = __builtin_amdgcn_mfma_f32_16x16x32_bf16(a[i], b3[j], acc_u[i][j], 0, 0, 0);
                }
        }
    }
    // epilogue: silu(h)*u -> LDS (stride 136) -> vectorized global stores
    __syncthreads();
#pragma unroll
    for (int i = 0; i < 4; i++)
#pragma unroll
        for (int j = 0; j < 4; j++)
#pragma unroll
            for (int r = 0; r < 4; r++) {
                int row = wm * 64 + i * 16 + quad * 4 + r;
                int col = wn * 64 + j * 16 + l15;
                float h = acc_h[i][j][r], u = acc_u[i][j][r];
                smem[row * 136 + col] = f2bf(h * u / (1.0f + __expf(-h)));
            }
    __syncthreads();
    int rt = tid >> 1, half = tid & 1;
    if (rt < rowsv) {
        u16* dp = Abuf + (size_t)(row0 + rt) * FDIM + bn * 128 + half * 64;
        const u16* sp = &smem[rt * 136 + half * 64];
#pragma unroll
        for (int q = 0; q < 8; q++)
            *(uint4*)(dp + q * 8) = *(const uint4*)(sp + q * 8);
    }
}

// ===================== GEMM2: Ybuf = Abuf @ W2t =====================
__launch_bounds__(256, 2)
__global__ void k_gemm2(const u16* __restrict__ Abuf, const u16* __restrict__ w2t,
                        const int* __restrict__ sched, u16* __restrict__ Ybuf) {
    __shared__ __align__(16) u16 smem[17408];     // max(32K staging, 34 KB epilogue)
    u16* sA = smem;                               // 128x64
    u16* sB = smem + 8192;                        // 128x64

    int bn = blockIdx.x;
    int bm = blockIdx.y;
    int total = sched[3 * MAXMT];
    if (bm >= total) return;
    int e = sched[bm];
    int row0 = sched[MAXMT + bm];
    int rowsv = sched[2 * MAXMT + bm];

    int tid = threadIdx.x;
    int wave = tid >> 6, lane = tid & 63;
    int wm = wave & 1, wn = wave >> 1;
    int quad = lane >> 4, l15 = lane & 15;
    int lsub = lane >> 3, slot = lane & 7;

    const u16* gA[4]; const u16* gB[4]; u16* lA[4]; u16* lB[4];
#pragma unroll
    for (int c = 0; c < 4; c++) {
        int row = c * 32 + wave * 8 + lsub;
        int cr = row < rowsv ? row : 0;
        int gch = slot ^ (row & 7);
        gA[c] = Abuf + (size_t)(row0 + cr) * FDIM + gch * 8;
        int dcol = bn * 128 + row;
        gB[c] = w2t + ((size_t)e * 1024 + dcol) * 1024 + gch * 8;
        lA[c] = sA + c * 2048 + wave * 512;
        lB[c] = sB + c * 2048 + wave * 512;
    }

    f32x4 acc[4][4];
#pragma unroll
    for (int i = 0; i < 4; i++)
#pragma unroll
        for (int j = 0; j < 4; j++) acc[i][j] = (f32x4)0.f;

    for (int kt = 0; kt < 16; ++kt) {
        int k0 = kt * 64;
        __syncthreads();
#pragma unroll
        for (int c = 0; c < 4; c++) {
            async_copy16(gA[c] + k0, lA[c]);
            async_copy16(gB[c] + k0, lB[c]);
        }
        __syncthreads();
#pragma unroll
        for (int kk = 0; kk < 2; ++kk) {
            bf16x8 a[4], b[4];
#pragma unroll
            for (int i = 0; i < 4; i++) {
                int m = wm * 64 + i * 16 + l15;
                int s = (kk * 4 + quad) ^ (m & 7);
                a[i] = *(const bf16x8*)&sA[m * 64 + s * 8];
            }
#pragma unroll
            for (int j = 0; j < 4; j++) {
                int nn = wn * 64 + j * 16 + l15;
                int s = (kk * 4 + quad) ^ (nn & 7);
                b[j] = *(const bf16x8*)&sB[nn * 64 + s * 8];
            }
#pragma unroll
            for (int i = 0; i < 4; i++)
#pragma unroll
                for (int j = 0; j < 4; j++)
                    acc[i][j] = __builtin_amdgcn_mfma_f32_16x16x32_bf16(a[i], b[j], acc[i][j], 0, 0, 0);
        }
    }
    __syncthreads();
#pragma unroll
    for (int i = 0; i < 4; i++)
#pragma unroll
        for (int j = 0; j < 4; j++)
#pragma unroll
            for (int r = 0; r < 4; r++) {
                int row = wm * 64 + i * 16 + quad * 4 + r;
                int col = wn * 64 + j * 16 + l15;
                smem[row * 136 + col] = f2bf(acc[i][j][r]);
            }
    __syncthreads();
    int rt = tid >> 1, half = tid & 1;
    if (rt < rowsv) {
        u16* dp = Ybuf + (size_t)(row0 + rt) * DDIM + bn * 128 + half * 64;
        const u16* sp = &smem[rt * 136 + half * 64];
#pragma unroll
        for (int q = 0; q < 8; q++)
            *(uint4*)(dp + q * 8) = *(const uint4*)(sp + q * 8);
    }
}

// ---------------- combine: out[n] = w0*Y[p0] + w1*Y[p1] ----------------
__global__ void k_combine(const u16* __restrict__ Y, const int* __restrict__ ppos,
                          const float* __restrict__ pwt, const int* __restrict__ dflag,
                          void* __restrict__ out) {
    int n = blockIdx.x, t = threadIdx.x;
    int p0 = ppos[2 * n], p1 = ppos[2 * n + 1];
    float w0 = pwt[p0], w1 = pwt[p1];
    uint2 a = *(const uint2*)(Y + (size_t)p0 * 1024 + t * 4);
    uint2 b = *(const uint2*)(Y + (size_t)p1 * 1024 + t * 4);
    const u16* ap = (const u16*)&a;
    const u16* bp = (const u16*)&b;
    float r[4];
#pragma unroll
    for (int j = 0; j < 4; j++) r[j] = w0 * bf2f(ap[j]) + w1 * bf2f(bp[j]);
    if (dflag[0]) {
        float4 o = { r[0], r[1], r[2], r[3] };
        *(float4*)((float*)out + (size_t)n * 1024 + t * 4) = o;
    } else {
        u16 o[4] = { f2bf(r[0]), f2bf(r[1]), f2bf(r[2]), f2bf(r[3]) };
        *(uint2*)((u16*)out + (size_t)n * 1024 + t * 4) = *(const uint2*)o;
    }
}

extern "C" void kernel_launch(void* const* d_in, const int* in_sizes, int n_in,
                              void* d_out, int out_size, void* d_ws, size_t ws_size,
                              hipStream_t stream) {
    const void* x  = d_in[0];
    const void* wg = d_in[1];
    const void* w1 = d_in[2];
    const void* w3 = d_in[3];
    const void* w2 = d_in[4];

    u16* w1t  = (u16*)d_ws;                  // 16 MB (reused as w2t after gemm13)
    u16* w3t  = w1t + (size_t)8 * 1048576;   // 16 MB
    u16* Abuf = w3t + (size_t)8 * 1048576;   // 8 MB
    u16* Ybuf = Abuf + (size_t)4096 * 1024;  // 8 MB
    u16* xb   = Ybuf + (size_t)4096 * 1024;  // 4 MB
    int*   te   = (int*)(xb + (size_t)N_TOK * DDIM);
    float* tw   = (float*)(te + 2 * N_TOK);
    int*   ptok = (int*)(tw + 2 * N_TOK);
    float* pwt  = (float*)(ptok + 2 * N_TOK);
    int*   ppos = (int*)(pwt + 2 * N_TOK);
    int*   sched = ppos + 2 * N_TOK;
    int*   dflag = sched + 128;
    u16* w2t = w1t;

    k_detect<<<1, 512, 0, stream>>>((const u16*)x, dflag);
    k_normx<<<2048, 256, 0, stream>>>(x, dflag, xb);
    k_gating<<<512, 256, 0, stream>>>(x, wg, dflag, d_out, te, tw);
    k_sched<<<1, 256, 0, stream>>>(te, tw, ptok, pwt, ppos, sched);

    k_transpose<<<dim3(16, 16, 8), 256, 0, stream>>>(w1, dflag, w1t);
    k_transpose<<<dim3(16, 16, 8), 256, 0, stream>>>(w3, dflag, w3t);
    k_gemm13<<<dim3(8, MAXMT), 256, 0, stream>>>(xb, w1t, w3t, ptok, sched, Abuf);
    k_transpose<<<dim3(16, 16, 8), 256, 0, stream>>>(w2, dflag, w2t);
    k_gemm2<<<dim3(8, MAXMT), 256, 0, stream>>>(Abuf, w2t, sched, Ybuf);

    k_combine<<<2048, 256, 0, stream>>>(Ybuf, ppos, pwt, dflag, d_out);
}

// Round 6
// 206.746 us; speedup vs baseline: 2.1143x; 1.1036x over previous
//
#include <hip/hip_runtime.h>
#include <stdint.h>

typedef unsigned short u16;
typedef __attribute__((ext_vector_type(8))) __bf16 bf16x8;
typedef __attribute__((ext_vector_type(4))) float f32x4;

#define MAXMT 40
#define N_TOK 2048
#define DDIM 1024
#define FDIM 1024

#define DEV static __device__ __forceinline__

DEV float bf2f(u16 u) {
    union { uint32_t i; float f; } v;
    v.i = ((uint32_t)u) << 16;
    return v.f;
}
DEV u16 f2bf(float f) {
    union { float f; uint32_t i; } v;
    v.f = f;
    uint32_t x = v.i;
    return (u16)((x + 0x7fffu + ((x >> 16) & 1u)) >> 16);  // RNE
}

// async global->LDS, 16B per lane; lds base wave-uniform, HW writes lane i at base+16*i
DEV void async_copy16(const u16* gsrc, u16* ldst) {
    __builtin_amdgcn_global_load_lds(
        (const __attribute__((address_space(1))) void*)(uintptr_t)gsrc,
        (__attribute__((address_space(3))) void*)(uint32_t)(uintptr_t)ldst,
        16, 0, 0);
}

// per-block dtype sniff: sample first 256 u16 of tensor; fp32-reinterpreted data has
// ~36% wild exponent fields, bf16 ~0%. Returns 1 => fp32.
DEV int sniff_fp(const void* p, int tid, int* scnt) {
    if (tid == 0) *scnt = 0;
    __syncthreads();
    u16 u = ((const u16*)p)[tid & 255];
    int e = (u >> 7) & 0xff;
    if (e != 0 && (e < 90 || e > 160)) atomicAdd(scnt, 1);
    __syncthreads();
    return *scnt > 64;
}

// ===================== mega: 3x8 weight transposes (z<24) + gating/normx (z>=24) =====================
__global__ void k_mega(const void* __restrict__ x, const void* __restrict__ wg,
                       const void* __restrict__ w1, const void* __restrict__ w3,
                       const void* __restrict__ w2, u16* __restrict__ wt,
                       u16* __restrict__ xb, void* __restrict__ out_base,
                       int* __restrict__ te, float* __restrict__ tw) {
    __shared__ int scnt;
    __shared__ __align__(16) u16 s[64][72];
    int z = blockIdx.z, tid = threadIdx.x;

    if (z < 24) {
        // ---- transpose plane: mat z; which tensor = z/8, local mat = z%8 ----
        int which = z >> 3, mat = z & 7;
        const void* src0 = which == 0 ? w1 : (which == 1 ? w3 : w2);
        int fp = sniff_fp(src0, tid, &scnt);
        u16* dst = wt + ((size_t)z) * 1048576;
        int r = tid >> 2, seg = tid & 3;
        int r0 = blockIdx.y * 64, c0 = blockIdx.x * 64;
        size_t base = (size_t)mat * 1048576 + (size_t)(r0 + r) * 1024 + c0 + seg * 16;
        u16 v[16];
        if (fp) {
            const float* sp = (const float*)src0 + base;
#pragma unroll
            for (int q = 0; q < 4; q++) {
                float4 f = ((const float4*)sp)[q];
                v[q * 4 + 0] = f2bf(f.x); v[q * 4 + 1] = f2bf(f.y);
                v[q * 4 + 2] = f2bf(f.z); v[q * 4 + 3] = f2bf(f.w);
            }
        } else {
            const u16* sp = (const u16*)src0 + base;
            *(uint4*)&v[0] = *(const uint4*)sp;
            *(uint4*)&v[8] = *(const uint4*)(sp + 8);
        }
        *(uint4*)&s[r][seg * 16] = *(const uint4*)&v[0];
        *(uint4*)&s[r][seg * 16 + 8] = *(const uint4*)&v[8];
        __syncthreads();
        u16 tmp[16];
#pragma unroll
        for (int j = 0; j < 16; j++) tmp[j] = s[seg * 16 + j][r];
        u16* dp = dst + (size_t)(c0 + r) * 1024 + r0 + seg * 16;
        *(uint4*)dp = *(const uint4*)&tmp[0];
        *(uint4*)(dp + 8) = *(const uint4*)&tmp[8];
    } else {
        // ---- gating plane: 512 blocks, 4 tokens each; also emits xb (bf16 x) ----
        int fp = sniff_fp(x, tid, &scnt);
        int gi = (z - 24) * 256 + blockIdx.y * 16 + blockIdx.x;
        int wave = tid >> 6, lane = tid & 63;
        int n = gi * 4 + wave;
        float acc[8];
#pragma unroll
        for (int e = 0; e < 8; e++) acc[e] = 0.f;
        if (fp) {
            const float* xp = (const float*)x + (size_t)n * DDIM;
            const float* wp = (const float*)wg;
            for (int it = 0; it < 16; ++it) {
                int d = it * 64 + lane;
                float xv = xp[d];
                xb[(size_t)n * DDIM + d] = f2bf(xv);
#pragma unroll
                for (int e = 0; e < 8; e++) acc[e] += xv * wp[e * DDIM + d];
            }
        } else {
            const u16* xp = (const u16*)x + (size_t)n * DDIM;
            const u16* wp = (const u16*)wg;
            for (int it = 0; it < 16; ++it) {
                int d = it * 64 + lane;
                u16 raw = xp[d];
                xb[(size_t)n * DDIM + d] = raw;
                float xv = bf2f(raw);
#pragma unroll
                for (int e = 0; e < 8; e++) acc[e] += xv * bf2f(wp[e * DDIM + d]);
            }
        }
#pragma unroll
        for (int e = 0; e < 8; e++) {
            for (int off = 32; off; off >>= 1) acc[e] += __shfl_xor(acc[e], off);
        }
        if (lane < 8) {
            if (fp) ((float*)out_base + (size_t)N_TOK * DDIM)[n * 8 + lane] = acc[lane];
            else    ((u16*)out_base + (size_t)N_TOK * DDIM)[n * 8 + lane] = f2bf(acc[lane]);
        }
        if (lane == 0) {
            int e0 = 0; float b0 = acc[0];
            for (int e = 1; e < 8; e++) if (acc[e] > b0) { b0 = acc[e]; e0 = e; }
            int e1 = -1; float b1 = -1e30f;
            for (int e = 0; e < 8; e++) if (e != e0 && acc[e] > b1) { b1 = acc[e]; e1 = e; }
            float m = fmaxf(b0, b1);
            float x0 = __expf(b0 - m), x1 = __expf(b1 - m);
            float sden = x0 + x1;
            te[n * 2] = e0; te[n * 2 + 1] = e1;
            tw[n * 2] = x0 / sden; tw[n * 2 + 1] = x1 / sden;
        }
    }
}

// ---------------- scheduling ----------------
__global__ void k_sched(const int* __restrict__ te, const float* __restrict__ tw,
                        int* __restrict__ pair_token, float* __restrict__ pair_weight,
                        int* __restrict__ ppos, int* __restrict__ sched) {
    __shared__ int cnt[8], cur[8];
    int t = threadIdx.x;
    if (t < 8) cnt[t] = 0;
    __syncthreads();
    for (int n = t; n < N_TOK; n += 256) {
        atomicAdd(&cnt[te[2 * n]], 1);
        atomicAdd(&cnt[te[2 * n + 1]], 1);
    }
    __syncthreads();
    if (t == 0) {
        int o = 0, mt = 0;
        for (int e = 0; e < 8; e++) {
            cur[e] = o;
            int c = cnt[e];
            for (int m0 = 0; m0 < c; m0 += 128) {
                sched[mt] = e;
                sched[MAXMT + mt] = o + m0;
                sched[2 * MAXMT + mt] = (c - m0 < 128) ? (c - m0) : 128;
                mt++;
            }
            o += c;
        }
        sched[3 * MAXMT] = mt;
        for (int i = mt; i < MAXMT; i++) { sched[i] = 0; sched[MAXMT + i] = 0; sched[2 * MAXMT + i] = 0; }
    }
    __syncthreads();
    for (int n = t; n < N_TOK; n += 256) {
#pragma unroll
        for (int s = 0; s < 2; s++) {
            int e = te[2 * n + s];
            int p = atomicAdd(&cur[e], 1);
            pair_token[p] = n;
            pair_weight[p] = tw[2 * n + s];
            ppos[2 * n + s] = p;
        }
    }
}

// ===================== fused SwiGLU GEMM: Abuf = silu(X@W1) * (X@W3) =====================
// Tile: 128 pairs x 64 f-cols, BK=64. LDS: sA 16K + sB1 8K + sB3 8K = 32 KB.
__launch_bounds__(256, 3)
__global__ void k_gemm13(const u16* __restrict__ xb, const u16* __restrict__ w1t,
                         const u16* __restrict__ w3t, const int* __restrict__ pair_token,
                         const int* __restrict__ sched, u16* __restrict__ Abuf) {
    __shared__ __align__(16) u16 smem[16384];     // 32 KB
    u16* sA  = smem;                              // 128x64
    u16* sB1 = smem + 8192;                       // 64x64
    u16* sB3 = smem + 12288;                      // 64x64

    int bn = blockIdx.x;          // 16 tiles of 64 cols
    int bm = blockIdx.y;
    int total = sched[3 * MAXMT];
    if (bm >= total) return;
    int e = sched[bm];
    int row0 = sched[MAXMT + bm];
    int rowsv = sched[2 * MAXMT + bm];

    int tid = threadIdx.x;
    int wave = tid >> 6, lane = tid & 63;
    int wm = wave & 1, wn = wave >> 1;            // wave: 64m x 32n
    int quad = lane >> 4, l15 = lane & 15;
    int lsub = lane >> 3, slot = lane & 7;

    const u16* gA[4]; u16* lA[4];
#pragma unroll
    for (int c = 0; c < 4; c++) {
        int row = c * 32 + wave * 8 + lsub;       // 0..127
        int cr = row < rowsv ? row : 0;
        int tok = pair_token[row0 + cr];
        int gch = slot ^ (row & 7);
        gA[c] = xb + (size_t)tok * DDIM + gch * 8;
        lA[c] = sA + c * 2048 + wave * 512;
    }
    const u16* gB1[2]; const u16* gB3[2]; int lBoff[2];
#pragma unroll
    for (int c = 0; c < 2; c++) {
        int row = c * 32 + wave * 8 + lsub;       // 0..63
        int gch = slot ^ (row & 7);
        int fcol = bn * 64 + row;
        gB1[c] = w1t + ((size_t)e * 1024 + fcol) * 1024 + gch * 8;
        gB3[c] = w3t + ((size_t)e * 1024 + fcol) * 1024 + gch * 8;
        lBoff[c] = c * 2048 + wave * 512;
    }

    f32x4 acc_h[4][2], acc_u[4][2];
#pragma unroll
    for (int i = 0; i < 4; i++)
#pragma unroll
        for (int j = 0; j < 2; j++) { acc_h[i][j] = (f32x4)0.f; acc_u[i][j] = (f32x4)0.f; }

    for (int kt = 0; kt < 16; ++kt) {
        int k0 = kt * 64;
        __syncthreads();
#pragma unroll
        for (int c = 0; c < 4; c++) async_copy16(gA[c] + k0, lA[c]);
#pragma unroll
        for (int c = 0; c < 2; c++) {
            async_copy16(gB1[c] + k0, sB1 + lBoff[c]);
            async_copy16(gB3[c] + k0, sB3 + lBoff[c]);
        }
        __syncthreads();
#pragma unroll
        for (int kk = 0; kk < 2; ++kk) {
            bf16x8 a[4], b1[2], b3[2];
#pragma unroll
            for (int i = 0; i < 4; i++) {
                int m = wm * 64 + i * 16 + l15;
                int s = (kk * 4 + quad) ^ (m & 7);
                a[i] = *(const bf16x8*)&sA[m * 64 + s * 8];
            }
#pragma unroll
            for (int j = 0; j < 2; j++) {
                int nn = wn * 32 + j * 16 + l15;
                int s = (kk * 4 + quad) ^ (nn & 7);
                b1[j] = *(const bf16x8*)&sB1[nn * 64 + s * 8];
                b3[j] = *(const bf16x8*)&sB3[nn * 64 + s * 8];
            }
#pragma unroll
            for (int i = 0; i < 4; i++)
#pragma unroll
                for (int j = 0; j < 2; j++) {
                    acc_h[i][j] = __builtin_amdgcn_mfma_f32_16x16x32_bf16(a[i], b1[j], acc_h[i][j], 0, 0, 0);
                    acc_u[i][j] = __builtin_amdgcn_mfma_f32_16x16x32_bf16(a[i], b3[j], acc_u[i][j], 0, 0, 0);
                }
        }
    }
    // epilogue: silu(h)*u -> LDS (stride 72) -> vectorized global stores
    __syncthreads();
#pragma unroll
    for (int i = 0; i < 4; i++)
#pragma unroll
        for (int j = 0; j < 2; j++)
#pragma unroll
            for (int r = 0; r < 4; r++) {
                int row = wm * 64 + i * 16 + quad * 4 + r;
                int col = wn * 32 + j * 16 + l15;
                float h = acc_h[i][j][r], u = acc_u[i][j][r];
                smem[row * 72 + col] = f2bf(h * u / (1.0f + __expf(-h)));
            }
    __syncthreads();
    int rt = tid >> 1, half = tid & 1;
    if (rt < rowsv) {
        u16* dp = Abuf + (size_t)(row0 + rt) * FDIM + bn * 64 + half * 32;
        const u16* sp = &smem[rt * 72 + half * 32];
#pragma unroll
        for (int q = 0; q < 4; q++)
            *(uint4*)(dp + q * 8) = *(const uint4*)(sp + q * 8);
    }
}

// ===================== GEMM2: Ybuf = Abuf @ W2t =====================
__launch_bounds__(256, 3)
__global__ void k_gemm2(const u16* __restrict__ Abuf, const u16* __restrict__ w2t,
                        const int* __restrict__ sched, u16* __restrict__ Ybuf) {
    __shared__ __align__(16) u16 smem[12288];     // 24 KB
    u16* sA = smem;                               // 128x64
    u16* sB = smem + 8192;                        // 64x64

    int bn = blockIdx.x;
    int bm = blockIdx.y;
    int total = sched[3 * MAXMT];
    if (bm >= total) return;
    int e = sched[bm];
    int row0 = sched[MAXMT + bm];
    int rowsv = sched[2 * MAXMT + bm];

    int tid = threadIdx.x;
    int wave = tid >> 6, lane = tid & 63;
    int wm = wave & 1, wn = wave >> 1;
    int quad = lane >> 4, l15 = lane & 15;
    int lsub = lane >> 3, slot = lane & 7;

    const u16* gA[4]; u16* lA[4];
#pragma unroll
    for (int c = 0; c < 4; c++) {
        int row = c * 32 + wave * 8 + lsub;
        int cr = row < rowsv ? row : 0;
        int gch = slot ^ (row & 7);
        gA[c] = Abuf + (size_t)(row0 + cr) * FDIM + gch * 8;
        lA[c] = sA + c * 2048 + wave * 512;
    }
    const u16* gB[2]; u16* lB[2];
#pragma unroll
    for (int c = 0; c < 2; c++) {
        int row = c * 32 + wave * 8 + lsub;
        int gch = slot ^ (row & 7);
        int dcol = bn * 64 + row;
        gB[c] = w2t + ((size_t)e * 1024 + dcol) * 1024 + gch * 8;
        lB[c] = sB + c * 2048 + wave * 512;
    }

    f32x4 acc[4][2];
#pragma unroll
    for (int i = 0; i < 4; i++)
#pragma unroll
        for (int j = 0; j < 2; j++) acc[i][j] = (f32x4)0.f;

    for (int kt = 0; kt < 16; ++kt) {
        int k0 = kt * 64;
        __syncthreads();
#pragma unroll
        for (int c = 0; c < 4; c++) async_copy16(gA[c] + k0, lA[c]);
#pragma unroll
        for (int c = 0; c < 2; c++) async_copy16(gB[c] + k0, lB[c]);
        __syncthreads();
#pragma unroll
        for (int kk = 0; kk < 2; ++kk) {
            bf16x8 a[4], b[2];
#pragma unroll
            for (int i = 0; i < 4; i++) {
                int m = wm * 64 + i * 16 + l15;
                int s = (kk * 4 + quad) ^ (m & 7);
                a[i] = *(const bf16x8*)&sA[m * 64 + s * 8];
            }
#pragma unroll
            for (int j = 0; j < 2; j++) {
                int nn = wn * 32 + j * 16 + l15;
                int s = (kk * 4 + quad) ^ (nn & 7);
                b[j] = *(const bf16x8*)&sB[nn * 64 + s * 8];
            }
#pragma unroll
            for (int i = 0; i < 4; i++)
#pragma unroll
                for (int j = 0; j < 2; j++)
                    acc[i][j] = __builtin_amdgcn_mfma_f32_16x16x32_bf16(a[i], b[j], acc[i][j], 0, 0, 0);
        }
    }
    __syncthreads();
#pragma unroll
    for (int i = 0; i < 4; i++)
#pragma unroll
        for (int j = 0; j < 2; j++)
#pragma unroll
            for (int r = 0; r < 4; r++) {
                int row = wm * 64 + i * 16 + quad * 4 + r;
                int col = wn * 32 + j * 16 + l15;
                smem[row * 72 + col] = f2bf(acc[i][j][r]);
            }
    __syncthreads();
    int rt = tid >> 1, half = tid & 1;
    if (rt < rowsv) {
        u16* dp = Ybuf + (size_t)(row0 + rt) * DDIM + bn * 64 + half * 32;
        const u16* sp = &smem[rt * 72 + half * 32];
#pragma unroll
        for (int q = 0; q < 4; q++)
            *(uint4*)(dp + q * 8) = *(const uint4*)(sp + q * 8);
    }
}

// ---------------- combine: out[n] = w0*Y[p0] + w1*Y[p1] ----------------
__global__ void k_combine(const u16* __restrict__ Y, const int* __restrict__ ppos,
                          const float* __restrict__ pwt, const void* __restrict__ x,
                          void* __restrict__ out) {
    __shared__ int scnt;
    int n = blockIdx.x, t = threadIdx.x;
    int fp = sniff_fp(x, t, &scnt);
    int p0 = ppos[2 * n], p1 = ppos[2 * n + 1];
    float w0 = pwt[p0], w1 = pwt[p1];
    uint2 a = *(const uint2*)(Y + (size_t)p0 * 1024 + t * 4);
    uint2 b = *(const uint2*)(Y + (size_t)p1 * 1024 + t * 4);
    const u16* ap = (const u16*)&a;
    const u16* bp = (const u16*)&b;
    float r[4];
#pragma unroll
    for (int j = 0; j < 4; j++) r[j] = w0 * bf2f(ap[j]) + w1 * bf2f(bp[j]);
    if (fp) {
        float4 o = { r[0], r[1], r[2], r[3] };
        *(float4*)((float*)out + (size_t)n * 1024 + t * 4) = o;
    } else {
        u16 o[4] = { f2bf(r[0]), f2bf(r[1]), f2bf(r[2]), f2bf(r[3]) };
        *(uint2*)((u16*)out + (size_t)n * 1024 + t * 4) = *(const uint2*)o;
    }
}

extern "C" void kernel_launch(void* const* d_in, const int* in_sizes, int n_in,
                              void* d_out, int out_size, void* d_ws, size_t ws_size,
                              hipStream_t stream) {
    const void* x  = d_in[0];
    const void* wg = d_in[1];
    const void* w1 = d_in[2];
    const void* w3 = d_in[3];
    const void* w2 = d_in[4];

    u16* wt   = (u16*)d_ws;                  // 48 MB: w1t(8 mats) | w3t | w2t
    u16* w1t  = wt;
    u16* w3t  = wt + (size_t)8 * 1048576;
    u16* w2t  = wt + (size_t)16 * 1048576;
    u16* Abuf = wt + (size_t)24 * 1048576;   // 8 MB
    u16* Ybuf = Abuf + (size_t)4096 * 1024;  // 8 MB
    u16* xb   = Ybuf + (size_t)4096 * 1024;  // 4 MB
    int*   te   = (int*)(xb + (size_t)N_TOK * DDIM);
    float* tw   = (float*)(te + 2 * N_TOK);
    int*   ptok = (int*)(tw + 2 * N_TOK);
    float* pwt  = (float*)(ptok + 2 * N_TOK);
    int*   ppos = (int*)(pwt + 2 * N_TOK);
    int*   sched = ppos + 2 * N_TOK;

    k_mega<<<dim3(16, 16, 26), 256, 0, stream>>>(x, wg, w1, w3, w2, wt, xb, d_out, te, tw);
    k_sched<<<1, 256, 0, stream>>>(te, tw, ptok, pwt, ppos, sched);
    k_gemm13<<<dim3(16, MAXMT), 256, 0, stream>>>(xb, w1t, w3t, ptok, sched, Abuf);
    k_gemm2<<<dim3(16, MAXMT), 256, 0, stream>>>(Abuf, w2t, sched, Ybuf);
    k_combine<<<2048, 256, 0, stream>>>(Ybuf, ppos, pwt, x, d_out);
}